// Round 3
// baseline (465.917 us; speedup 1.0000x reference)
//
#include <hip/hip_runtime.h>

typedef __attribute__((ext_vector_type(8))) short bf16x8;
typedef __attribute__((ext_vector_type(4))) float f32x4;
typedef __attribute__((ext_vector_type(4))) unsigned int u32x4;

__device__ __forceinline__ short f2bf(float f) {
    union { float f; unsigned u; } v; v.f = f;
    unsigned r = (v.u + 0x7FFFu + ((v.u >> 16) & 1u)) >> 16;  // RNE
    return (short)r;
}

__device__ __forceinline__ float sigmoidf(float x) {
    return 1.0f / (1.0f + __expf(-x));
}

constexpr int S = 200, E = 128, A = 64;
constexpr int NSTRIP = 13;          // ceil(200/16)
constexpr int WFRAG_SHORTS = 16384; // K=256 x N=64 bf16, frag-linear

// ---------------- kernel 0: precompute frag weights + per-batch bias ----------
// grid 513: block 512 builds the 32KB frag-layout weight buffer
//           blocks 0..511 build beta for 4 batches each
__global__ __launch_bounds__(256) void precomp(
    const float* __restrict__ target,
    const float* __restrict__ W1,
    const float* __restrict__ b1,
    short* __restrict__ wfrag,      // d_ws, 32 KB
    float* __restrict__ beta)       // d_ws+32KB, 2048*64 fp32
{
    const int tid = threadIdx.x;
    if (blockIdx.x == 512) {
        // Wcat[k][n]: k<128 -> W1a+W1d ; k>=128 -> W1c (e=k-128)
        for (int i = tid; i < WFRAG_SHORTS; i += 256) {
            const int j = i & 7, ln = (i >> 3) & 63, f = i >> 9;
            const int kt = f >> 2, nt = f & 3;
            const int n = nt * 16 + (ln & 15);
            const int k = kt * 32 + (ln >> 4) * 8 + j;
            const float v = (k < 128)
                ? W1[k * A + n] + W1[(384 + k) * A + n]
                : W1[(128 + k) * A + n];             // 256 + (k-128)
            wfrag[i] = f2bf(v);
        }
    } else {
        const int b = blockIdx.x * 4 + (tid >> 6);
        const int a = tid & 63;
        const float* tp = target + (size_t)b * E;
        float acc = b1[a];
        #pragma unroll 8
        for (int e = 0; e < E; ++e)
            acc += tp[e] * (W1[(128 + e) * A + a] - W1[(384 + e) * A + a]);
        beta[b * A + a] = acc;
    }
}

// ---------------- kernel 1: fused attention, zero per-block weight setup ------
__global__ __launch_bounds__(256, 3) void attn_fused(
    const float* __restrict__ behaviors,
    const float* __restrict__ target,
    const float* __restrict__ W2,
    const float* __restrict__ b2,
    const short* __restrict__ wfrag,
    const float* __restrict__ beta,
    float* __restrict__ out)
{
    __shared__ short wb_f[WFRAG_SHORTS];  // 32 KB frag-linear weights
    __shared__ float red[4 * 128];        // 2 KB final reduction

    const int tid  = threadIdx.x;
    const int bat  = blockIdx.x;
    const int lane = tid & 63;
    const int wave = tid >> 6;
    const int l15  = lane & 15;
    const int quad = lane >> 4;

    // stage weights (L2-hot, 32KB): 2048 x 16B
    {
        const u32x4* src = (const u32x4*)wfrag;
        u32x4* dst = (u32x4*)wb_f;
        #pragma unroll
        for (int i = 0; i < 8; ++i) dst[tid + i * 256] = src[tid + i * 256];
    }

    // per-lane t slice (fp32), loop-invariant
    const float* tp = target + (size_t)bat * E;
    f32x4 tv[4][2];
    #pragma unroll
    for (int kt = 0; kt < 4; ++kt) {
        tv[kt][0] = *(const f32x4*)(tp + kt * 32 + quad * 8);
        tv[kt][1] = *(const f32x4*)(tp + kt * 32 + quad * 8 + 4);
    }

    float bias_l[4], w2_l[4];
    #pragma unroll
    for (int nt = 0; nt < 4; ++nt) {
        bias_l[nt] = beta[(size_t)bat * A + nt * 16 + l15];
        w2_l[nt]   = W2[nt * 16 + l15];
    }
    const float b2v = b2[0];
    const float* bptr = behaviors + (size_t)bat * S * E;

    __syncthreads();   // weights staged

    f32x4 oacc[4][2];
    #pragma unroll
    for (int kt = 0; kt < 4; ++kt) {
        oacc[kt][0] = f32x4{0.f, 0.f, 0.f, 0.f};
        oacc[kt][1] = f32x4{0.f, 0.f, 0.f, 0.f};
    }

    for (int st = wave; st < NSTRIP; st += 4) {
        const int row = st * 16 + l15;
        const bool valid = (row < S);
        const float* rp = bptr + (size_t)row * E + quad * 8;

        f32x4 av[4][2];
        #pragma unroll
        for (int kt = 0; kt < 4; ++kt) {
            av[kt][0] = f32x4{0.f, 0.f, 0.f, 0.f};
            av[kt][1] = f32x4{0.f, 0.f, 0.f, 0.f};
        }
        if (valid) {
            #pragma unroll
            for (int kt = 0; kt < 4; ++kt) {
                av[kt][0] = __builtin_nontemporal_load((const f32x4*)(rp + kt * 32));
                av[kt][1] = __builtin_nontemporal_load((const f32x4*)(rp + kt * 32 + 4));
            }
        }

        f32x4 acc[4];
        #pragma unroll
        for (int nt = 0; nt < 4; ++nt) acc[nt] = f32x4{0.f, 0.f, 0.f, 0.f};

        #pragma unroll
        for (int kt = 0; kt < 4; ++kt) {
            bf16x8 af, af2;
            #pragma unroll
            for (int h = 0; h < 2; ++h) {
                #pragma unroll
                for (int c = 0; c < 4; ++c) {
                    af[h * 4 + c]  = f2bf(av[kt][h][c]);
                    af2[h * 4 + c] = f2bf(av[kt][h][c] * tv[kt][h][c]);
                }
            }
            #pragma unroll
            for (int nt = 0; nt < 4; ++nt) {
                bf16x8 bf1 = *(const bf16x8*)&wb_f[(kt * 4 + nt) * 512 + lane * 8];
                acc[nt] = __builtin_amdgcn_mfma_f32_16x16x32_bf16(af, bf1, acc[nt], 0, 0, 0);
            }
            #pragma unroll
            for (int nt = 0; nt < 4; ++nt) {
                bf16x8 bf2 = *(const bf16x8*)&wb_f[((kt + 4) * 4 + nt) * 512 + lane * 8];
                acc[nt] = __builtin_amdgcn_mfma_f32_16x16x32_bf16(af2, bf2, acc[nt], 0, 0, 0);
            }
        }

        // logits: C row = quad*4+reg, col = nt*16+l15; reduce over 16 a-lanes
        float wgt[4];
        #pragma unroll
        for (int reg = 0; reg < 4; ++reg) {
            float p = 0.f;
            #pragma unroll
            for (int nt = 0; nt < 4; ++nt) {
                const float h = acc[nt][reg] + bias_l[nt];
                p += fmaxf(h, 0.f) * w2_l[nt];
            }
            p += __shfl_xor(p, 1, 64);
            p += __shfl_xor(p, 2, 64);
            p += __shfl_xor(p, 4, 64);
            p += __shfl_xor(p, 8, 64);
            wgt[reg] = sigmoidf(p + b2v);
        }

        // my row's weight: row base+l15 lives in quad l15>>2, element l15&3
        const int srcl = (l15 >> 2) << 4;
        const float t0 = __shfl(wgt[0], srcl, 64);
        const float t1 = __shfl(wgt[1], srcl, 64);
        const float t2 = __shfl(wgt[2], srcl, 64);
        const float t3 = __shfl(wgt[3], srcl, 64);
        const float wl = (l15 & 2) ? ((l15 & 1) ? t3 : t2)
                                   : ((l15 & 1) ? t1 : t0);

        #pragma unroll
        for (int kt = 0; kt < 4; ++kt) {
            #pragma unroll
            for (int h = 0; h < 2; ++h) {
                oacc[kt][h][0] += wl * av[kt][h][0];
                oacc[kt][h][1] += wl * av[kt][h][1];
                oacc[kt][h][2] += wl * av[kt][h][2];
                oacc[kt][h][3] += wl * av[kt][h][3];
            }
        }
    }

    // reduce oacc over the 16 rows (l15 lanes) of each quad
    #pragma unroll
    for (int kt = 0; kt < 4; ++kt)
        #pragma unroll
        for (int h = 0; h < 2; ++h)
            #pragma unroll
            for (int c = 0; c < 4; ++c) {
                float v = oacc[kt][h][c];
                v += __shfl_xor(v, 1, 64);
                v += __shfl_xor(v, 2, 64);
                v += __shfl_xor(v, 4, 64);
                v += __shfl_xor(v, 8, 64);
                oacc[kt][h][c] = v;
            }

    if (l15 == 0) {
        #pragma unroll
        for (int kt = 0; kt < 4; ++kt) {
            *(f32x4*)&red[wave * 128 + kt * 32 + quad * 8]     = oacc[kt][0];
            *(f32x4*)&red[wave * 128 + kt * 32 + quad * 8 + 4] = oacc[kt][1];
        }
    }
    __syncthreads();
    if (tid < E) {
        out[(size_t)bat * E + tid] =
            red[tid] + red[128 + tid] + red[256 + tid] + red[384 + tid];
    }
}

extern "C" void kernel_launch(void* const* d_in, const int* in_sizes, int n_in,
                              void* d_out, int out_size, void* d_ws, size_t ws_size,
                              hipStream_t stream) {
    const float* behaviors = (const float*)d_in[0];
    const float* target    = (const float*)d_in[1];
    const float* W1        = (const float*)d_in[2];
    const float* b1        = (const float*)d_in[3];
    const float* W2        = (const float*)d_in[4];
    const float* b2        = (const float*)d_in[5];
    float* out = (float*)d_out;

    short* wfrag = (short*)d_ws;
    float* beta  = (float*)((char*)d_ws + WFRAG_SHORTS * sizeof(short));

    hipLaunchKernelGGL(precomp, dim3(513), dim3(256), 0, stream,
                       target, W1, b1, wfrag, beta);
    hipLaunchKernelGGL(attn_fused, dim3(2048), dim3(256), 0, stream,
                       behaviors, target, W2, b2, wfrag, beta, out);
}

// Round 4
// 440.547 us; speedup vs baseline: 1.0576x; 1.0576x over previous
//
#include <hip/hip_runtime.h>

typedef __attribute__((ext_vector_type(8))) short bf16x8;
typedef __attribute__((ext_vector_type(4))) float f32x4;
typedef __attribute__((ext_vector_type(4))) unsigned int u32x4;

__device__ __forceinline__ short f2bf(float f) {
    union { float f; unsigned u; } v; v.f = f;
    unsigned r = (v.u + 0x7FFFu + ((v.u >> 16) & 1u)) >> 16;  // RNE
    return (short)r;
}

__device__ __forceinline__ float sigmoidf(float x) {
    return 1.0f / (1.0f + __expf(-x));
}

constexpr int S = 200, E = 128, A = 64;
constexpr int NSTRIP = 13;          // ceil(200/16)
constexpr int WFRAG_SHORTS = 16384; // K=256 x N=64 bf16, frag-linear

// ---------------- kernel 0: precompute frag weights + per-batch bias ----------
__global__ __launch_bounds__(256) void precomp(
    const float* __restrict__ target,
    const float* __restrict__ W1,
    const float* __restrict__ b1,
    short* __restrict__ wfrag,      // d_ws, 32 KB
    float* __restrict__ beta)       // d_ws+32KB, 2048*64 fp32
{
    const int tid = threadIdx.x;
    if (blockIdx.x == 512) {
        // Wcat[k][n]: k<128 -> W1a+W1d ; k>=128 -> W1c (e=k-128)
        for (int i = tid; i < WFRAG_SHORTS; i += 256) {
            const int j = i & 7, ln = (i >> 3) & 63, f = i >> 9;
            const int kt = f >> 2, nt = f & 3;
            const int n = nt * 16 + (ln & 15);
            const int k = kt * 32 + (ln >> 4) * 8 + j;
            const float v = (k < 128)
                ? W1[k * A + n] + W1[(384 + k) * A + n]
                : W1[(128 + k) * A + n];             // 256 + (k-128)
            wfrag[i] = f2bf(v);
        }
    } else {
        const int b = blockIdx.x * 4 + (tid >> 6);
        const int a = tid & 63;
        const float* tp = target + (size_t)b * E;
        float acc = b1[a];
        #pragma unroll 8
        for (int e = 0; e < E; ++e)
            acc += tp[e] * (W1[(128 + e) * A + a] - W1[(384 + e) * A + a]);
        beta[b * A + a] = acc;
    }
}

// ---------------- helpers ----------------
__device__ __forceinline__ void load_strip(f32x4 av[4][2], const float* __restrict__ bptr,
                                           int st, int l15, int quad)
{
    #pragma unroll
    for (int kt = 0; kt < 4; ++kt) {
        av[kt][0] = f32x4{0.f, 0.f, 0.f, 0.f};
        av[kt][1] = f32x4{0.f, 0.f, 0.f, 0.f};
    }
    const int row = st * 16 + l15;
    if (st < NSTRIP && row < S) {
        const float* rp = bptr + (size_t)row * E + quad * 8;
        #pragma unroll
        for (int kt = 0; kt < 4; ++kt) {
            av[kt][0] = *(const f32x4*)(rp + kt * 32);
            av[kt][1] = *(const f32x4*)(rp + kt * 32 + 4);
        }
    }
}

__device__ __forceinline__ void strip_compute(
    const f32x4 av[4][2], const f32x4 tv[4][2], f32x4 oacc[4][2],
    const short* __restrict__ wb_f,
    const float bias_l[4], const float w2_l[4], float b2v,
    int lane, int l15)
{
    f32x4 acc[4];
    #pragma unroll
    for (int nt = 0; nt < 4; ++nt) acc[nt] = f32x4{0.f, 0.f, 0.f, 0.f};

    #pragma unroll
    for (int kt = 0; kt < 4; ++kt) {
        bf16x8 af, af2;
        #pragma unroll
        for (int h = 0; h < 2; ++h) {
            #pragma unroll
            for (int c = 0; c < 4; ++c) {
                af[h * 4 + c]  = f2bf(av[kt][h][c]);
                af2[h * 4 + c] = f2bf(av[kt][h][c] * tv[kt][h][c]);
            }
        }
        #pragma unroll
        for (int nt = 0; nt < 4; ++nt) {
            bf16x8 bf1 = *(const bf16x8*)&wb_f[(kt * 4 + nt) * 512 + lane * 8];
            acc[nt] = __builtin_amdgcn_mfma_f32_16x16x32_bf16(af, bf1, acc[nt], 0, 0, 0);
        }
        #pragma unroll
        for (int nt = 0; nt < 4; ++nt) {
            bf16x8 bf2 = *(const bf16x8*)&wb_f[((kt + 4) * 4 + nt) * 512 + lane * 8];
            acc[nt] = __builtin_amdgcn_mfma_f32_16x16x32_bf16(af2, bf2, acc[nt], 0, 0, 0);
        }
    }

    // logits: C row = quad*4+reg, col = nt*16+l15; reduce over 16 a-lanes
    float wgt[4];
    #pragma unroll
    for (int reg = 0; reg < 4; ++reg) {
        float p = 0.f;
        #pragma unroll
        for (int nt = 0; nt < 4; ++nt) {
            const float h = acc[nt][reg] + bias_l[nt];
            p += fmaxf(h, 0.f) * w2_l[nt];
        }
        p += __shfl_xor(p, 1, 64);
        p += __shfl_xor(p, 2, 64);
        p += __shfl_xor(p, 4, 64);
        p += __shfl_xor(p, 8, 64);
        wgt[reg] = sigmoidf(p + b2v);
    }

    // my row's weight: row base+l15 lives in quad l15>>2, element l15&3
    const int srcl = (l15 >> 2) << 4;
    const float t0 = __shfl(wgt[0], srcl, 64);
    const float t1 = __shfl(wgt[1], srcl, 64);
    const float t2 = __shfl(wgt[2], srcl, 64);
    const float t3 = __shfl(wgt[3], srcl, 64);
    const float wl = (l15 & 2) ? ((l15 & 1) ? t3 : t2)
                               : ((l15 & 1) ? t1 : t0);

    #pragma unroll
    for (int kt = 0; kt < 4; ++kt) {
        #pragma unroll
        for (int h = 0; h < 2; ++h) {
            oacc[kt][h][0] += wl * av[kt][h][0];
            oacc[kt][h][1] += wl * av[kt][h][1];
            oacc[kt][h][2] += wl * av[kt][h][2];
            oacc[kt][h][3] += wl * av[kt][h][3];
        }
    }
}

// ---------------- kernel 1: fused attention, prefetch double-buffered ---------
__global__ __launch_bounds__(256, 4) void attn_fused(
    const float* __restrict__ behaviors,
    const float* __restrict__ target,
    const float* __restrict__ W2,
    const float* __restrict__ b2,
    const short* __restrict__ wfrag,
    const float* __restrict__ beta,
    float* __restrict__ out)
{
    __shared__ short wb_f[WFRAG_SHORTS];  // 32 KB frag-linear weights
    __shared__ float red[4 * 128];        // 2 KB final reduction

    const int tid  = threadIdx.x;
    const int bat  = blockIdx.x;
    const int lane = tid & 63;
    const int wave = tid >> 6;
    const int l15  = lane & 15;
    const int quad = lane >> 4;

    // stage weights (L2-hot, 32KB): 2048 x 16B
    {
        const u32x4* src = (const u32x4*)wfrag;
        u32x4* dst = (u32x4*)wb_f;
        #pragma unroll
        for (int i = 0; i < 8; ++i) dst[tid + i * 256] = src[tid + i * 256];
    }

    // per-lane t slice (fp32), loop-invariant
    const float* tp = target + (size_t)bat * E;
    f32x4 tv[4][2];
    #pragma unroll
    for (int kt = 0; kt < 4; ++kt) {
        tv[kt][0] = *(const f32x4*)(tp + kt * 32 + quad * 8);
        tv[kt][1] = *(const f32x4*)(tp + kt * 32 + quad * 8 + 4);
    }

    float bias_l[4], w2_l[4];
    #pragma unroll
    for (int nt = 0; nt < 4; ++nt) {
        bias_l[nt] = beta[(size_t)bat * A + nt * 16 + l15];
        w2_l[nt]   = W2[nt * 16 + l15];
    }
    const float b2v = b2[0];
    const float* bptr = behaviors + (size_t)bat * S * E;

    __syncthreads();   // weights staged

    f32x4 oacc[4][2];
    #pragma unroll
    for (int kt = 0; kt < 4; ++kt) {
        oacc[kt][0] = f32x4{0.f, 0.f, 0.f, 0.f};
        oacc[kt][1] = f32x4{0.f, 0.f, 0.f, 0.f};
    }

    // software-pipelined strip loop: issue strip s+4 loads before computing s
    f32x4 avA[4][2], avB[4][2];
    load_strip(avA, bptr, wave, l15, quad);
    #pragma unroll
    for (int it = 0; it < 4; ++it) {
        const int st = wave + it * 4;
        if (st >= NSTRIP) break;
        if ((it & 1) == 0) {
            load_strip(avB, bptr, st + 4, l15, quad);
            strip_compute(avA, tv, oacc, wb_f, bias_l, w2_l, b2v, lane, l15);
        } else {
            load_strip(avA, bptr, st + 4, l15, quad);
            strip_compute(avB, tv, oacc, wb_f, bias_l, w2_l, b2v, lane, l15);
        }
    }

    // reduce oacc over the 16 rows (l15 lanes) of each quad
    #pragma unroll
    for (int kt = 0; kt < 4; ++kt)
        #pragma unroll
        for (int h = 0; h < 2; ++h)
            #pragma unroll
            for (int c = 0; c < 4; ++c) {
                float v = oacc[kt][h][c];
                v += __shfl_xor(v, 1, 64);
                v += __shfl_xor(v, 2, 64);
                v += __shfl_xor(v, 4, 64);
                v += __shfl_xor(v, 8, 64);
                oacc[kt][h][c] = v;
            }

    if (l15 == 0) {
        #pragma unroll
        for (int kt = 0; kt < 4; ++kt) {
            *(f32x4*)&red[wave * 128 + kt * 32 + quad * 8]     = oacc[kt][0];
            *(f32x4*)&red[wave * 128 + kt * 32 + quad * 8 + 4] = oacc[kt][1];
        }
    }
    __syncthreads();
    if (tid < E) {
        out[(size_t)bat * E + tid] =
            red[tid] + red[128 + tid] + red[256 + tid] + red[384 + tid];
    }
}

extern "C" void kernel_launch(void* const* d_in, const int* in_sizes, int n_in,
                              void* d_out, int out_size, void* d_ws, size_t ws_size,
                              hipStream_t stream) {
    const float* behaviors = (const float*)d_in[0];
    const float* target    = (const float*)d_in[1];
    const float* W1        = (const float*)d_in[2];
    const float* b1        = (const float*)d_in[3];
    const float* W2        = (const float*)d_in[4];
    const float* b2        = (const float*)d_in[5];
    float* out = (float*)d_out;

    short* wfrag = (short*)d_ws;
    float* beta  = (float*)((char*)d_ws + WFRAG_SHORTS * sizeof(short));

    hipLaunchKernelGGL(precomp, dim3(513), dim3(256), 0, stream,
                       target, W1, b1, wfrag, beta);
    hipLaunchKernelGGL(attn_fused, dim3(2048), dim3(256), 0, stream,
                       behaviors, target, W2, b2, wfrag, beta, out);
}

// Round 5
// 354.046 us; speedup vs baseline: 1.3160x; 1.2443x over previous
//
#include <hip/hip_runtime.h>

typedef __attribute__((ext_vector_type(8))) short bf16x8;
typedef __attribute__((ext_vector_type(4))) float f32x4;

__device__ __forceinline__ short f2bf(float f) {
    union { float f; unsigned u; } v; v.f = f;
    unsigned r = (v.u + 0x7FFFu + ((v.u >> 16) & 1u)) >> 16;  // RNE
    return (short)r;
}

__device__ __forceinline__ float sigmoidf(float x) {
    return 1.0f / (1.0f + __expf(-x));
}

constexpr int S = 200, E = 128, A = 64;
constexpr int NSTRIP = 13;   // ceil(200/16)

__device__ __forceinline__ void load_strip(f32x4 av[4][2], const float* __restrict__ bptr,
                                           int st, int l15, int quad)
{
    #pragma unroll
    for (int kt = 0; kt < 4; ++kt) {
        av[kt][0] = f32x4{0.f, 0.f, 0.f, 0.f};
        av[kt][1] = f32x4{0.f, 0.f, 0.f, 0.f};
    }
    const int row = st * 16 + l15;
    if (st < NSTRIP && row < S) {
        const float* rp = bptr + (size_t)row * E + quad * 8;
        #pragma unroll
        for (int kt = 0; kt < 4; ++kt) {
            av[kt][0] = *(const f32x4*)(rp + kt * 32);
            av[kt][1] = *(const f32x4*)(rp + kt * 32 + 4);
        }
    }
}

// Single fused kernel. Per-batch K=128 weights Wb[e][a] = W1a+W1d+t[e]*W1c in
// frag-linear LDS layout (conflict-free ds_read_b128); bias beta = b1 + t@(W1b-W1d).
__global__ __launch_bounds__(256, 4) void attn_fused(
    const float* __restrict__ behaviors,
    const float* __restrict__ target,
    const float* __restrict__ W1,
    const float* __restrict__ b1,
    const float* __restrict__ W2,
    const float* __restrict__ b2,
    float* __restrict__ out)
{
    __shared__ short wb_f[16 * 512];   // 16 KB frag-linear bf16 Wb (K=128,N=64)
    __shared__ short wbtmp[E * A];     // 16 KB [e][a] staging
    __shared__ float red[4 * 128];     // 2 KB bias partials / final reduction
    __shared__ float t_lds[E];
    __shared__ float bias_lds[A];
    __shared__ float w2_lds[A];

    const int tid  = threadIdx.x;
    const int bat  = blockIdx.x;
    const int lane = tid & 63;
    const int wave = tid >> 6;
    const int l15  = lane & 15;
    const int quad = lane >> 4;

    const float* bptr = behaviors + (size_t)bat * S * E;

    // issue first strip's global loads BEFORE setup (hides setup latency)
    f32x4 avA[4][2], avB[4][2];
    load_strip(avA, bptr, wave, l15, quad);

    if (tid < E) t_lds[tid] = target[(size_t)bat * E + tid];
    __syncthreads();

    // Wb[e][a] bf16, coalesced W1 reads (256B rows, L2-hot)
    for (int i = tid; i < E * A; i += 256) {
        const int e = i >> 6, a = i & 63;
        wbtmp[i] = f2bf(W1[e * A + a] + W1[(384 + e) * A + a]
                        + t_lds[e] * W1[(256 + e) * A + a]);
    }
    // beta partials: 4 e-segments of 32
    {
        const int a = tid & 63, seg = tid >> 6;
        float acc = 0.f;
        #pragma unroll 8
        for (int e = seg * 32; e < seg * 32 + 32; ++e)
            acc += t_lds[e] * (W1[(128 + e) * A + a] - W1[(384 + e) * A + a]);
        red[seg * 64 + a] = acc;
    }
    __syncthreads();
    if (tid < A) {
        bias_lds[tid] = b1[tid] + red[tid] + red[64 + tid] + red[128 + tid] + red[192 + tid];
        w2_lds[tid] = W2[tid];
    }
    // rearrange Wb -> frag-linear: frag f=(kt*4+nt), slot lane*8+j
    for (int i = tid; i < E * A; i += 256) {
        const int j = i & 7, ln = (i >> 3) & 63, f = i >> 9;
        const int kt = f >> 2, nt = f & 3;
        const int n = nt * 16 + (ln & 15);
        const int k = kt * 32 + (ln >> 4) * 8 + j;
        wb_f[i] = wbtmp[k * A + n];
    }
    __syncthreads();

    float bias_l[4], w2_l[4];
    #pragma unroll
    for (int nt = 0; nt < 4; ++nt) {
        bias_l[nt] = bias_lds[nt * 16 + l15];
        w2_l[nt]   = w2_lds[nt * 16 + l15];
    }
    const float b2v = b2[0];

    f32x4 oacc[4][2];
    #pragma unroll
    for (int kt = 0; kt < 4; ++kt) {
        oacc[kt][0] = f32x4{0.f, 0.f, 0.f, 0.f};
        oacc[kt][1] = f32x4{0.f, 0.f, 0.f, 0.f};
    }

    // strip loop, double-buffered (issue s+4 before computing s)
    #pragma unroll
    for (int it = 0; it < 4; ++it) {
        const int st = wave + it * 4;
        if (st >= NSTRIP) break;
        f32x4 (*cur)[2] = (it & 1) ? avB : avA;
        f32x4 (*nxt)[2] = (it & 1) ? avA : avB;
        load_strip(nxt, bptr, st + 4, l15, quad);

        f32x4 acc[4];
        #pragma unroll
        for (int nt = 0; nt < 4; ++nt) acc[nt] = f32x4{0.f, 0.f, 0.f, 0.f};

        #pragma unroll
        for (int kt = 0; kt < 4; ++kt) {
            bf16x8 af;
            #pragma unroll
            for (int h = 0; h < 2; ++h)
                #pragma unroll
                for (int c = 0; c < 4; ++c)
                    af[h * 4 + c] = f2bf(cur[kt][h][c]);
            #pragma unroll
            for (int nt = 0; nt < 4; ++nt) {
                bf16x8 bf1 = *(const bf16x8*)&wb_f[(kt * 4 + nt) * 512 + lane * 8];
                acc[nt] = __builtin_amdgcn_mfma_f32_16x16x32_bf16(af, bf1, acc[nt], 0, 0, 0);
            }
        }

        // logits: C row = quad*4+reg, col = nt*16+l15; reduce over 16 a-lanes
        float wgt[4];
        #pragma unroll
        for (int reg = 0; reg < 4; ++reg) {
            float p = 0.f;
            #pragma unroll
            for (int nt = 0; nt < 4; ++nt) {
                const float h = acc[nt][reg] + bias_l[nt];
                p += fmaxf(h, 0.f) * w2_l[nt];
            }
            p += __shfl_xor(p, 1, 64);
            p += __shfl_xor(p, 2, 64);
            p += __shfl_xor(p, 4, 64);
            p += __shfl_xor(p, 8, 64);
            wgt[reg] = sigmoidf(p + b2v);
        }

        // my row's weight: row base+l15 lives in quad l15>>2, element l15&3
        const int srcl = (l15 >> 2) << 4;
        const float t0 = __shfl(wgt[0], srcl, 64);
        const float t1 = __shfl(wgt[1], srcl, 64);
        const float t2 = __shfl(wgt[2], srcl, 64);
        const float t3 = __shfl(wgt[3], srcl, 64);
        const float wl = (l15 & 2) ? ((l15 & 1) ? t3 : t2)
                                   : ((l15 & 1) ? t1 : t0);

        #pragma unroll
        for (int kt = 0; kt < 4; ++kt)
            #pragma unroll
            for (int h = 0; h < 2; ++h) {
                oacc[kt][h][0] += wl * cur[kt][h][0];
                oacc[kt][h][1] += wl * cur[kt][h][1];
                oacc[kt][h][2] += wl * cur[kt][h][2];
                oacc[kt][h][3] += wl * cur[kt][h][3];
            }
    }

    // reduce oacc over the 16 rows (l15 lanes) of each quad
    #pragma unroll
    for (int kt = 0; kt < 4; ++kt)
        #pragma unroll
        for (int h = 0; h < 2; ++h)
            #pragma unroll
            for (int c = 0; c < 4; ++c) {
                float v = oacc[kt][h][c];
                v += __shfl_xor(v, 1, 64);
                v += __shfl_xor(v, 2, 64);
                v += __shfl_xor(v, 4, 64);
                v += __shfl_xor(v, 8, 64);
                oacc[kt][h][c] = v;
            }

    if (l15 == 0) {
        #pragma unroll
        for (int kt = 0; kt < 4; ++kt) {
            *(f32x4*)&red[wave * 128 + kt * 32 + quad * 8]     = oacc[kt][0];
            *(f32x4*)&red[wave * 128 + kt * 32 + quad * 8 + 4] = oacc[kt][1];
        }
    }
    __syncthreads();
    if (tid < E) {
        out[(size_t)bat * E + tid] =
            red[tid] + red[128 + tid] + red[256 + tid] + red[384 + tid];
    }
}

extern "C" void kernel_launch(void* const* d_in, const int* in_sizes, int n_in,
                              void* d_out, int out_size, void* d_ws, size_t ws_size,
                              hipStream_t stream) {
    const float* behaviors = (const float*)d_in[0];
    const float* target    = (const float*)d_in[1];
    const float* W1        = (const float*)d_in[2];
    const float* b1        = (const float*)d_in[3];
    const float* W2        = (const float*)d_in[4];
    const float* b2        = (const float*)d_in[5];
    float* out = (float*)d_out;

    hipLaunchKernelGGL(attn_fused, dim3(2048), dim3(256), 0, stream,
                       behaviors, target, W1, b1, W2, b2, out);
}